// Round 5
// baseline (341.351 us; speedup 1.0000x reference)
//
#include <hip/hip_runtime.h>
#include <hip/hip_bf16.h>

typedef __hip_bfloat16 bf16;
typedef __attribute__((ext_vector_type(8))) short short8;   // 8 bf16 = 4 VGPRs
typedef __attribute__((ext_vector_type(4))) short short4v;  // 4 bf16 = 2 VGPRs
typedef __attribute__((ext_vector_type(4))) float f32x4;    // MFMA C/D

#define BB 4
#define NN 2048
#define DD 256
#define HH 8
#define HD 32
#define BN (BB*NN)          // 8192
#define ELEMS (BN*DD)       // 2097152

// ---------------------------------------------------------------------------
// Scratch in module .bss (~25 MB).
// ---------------------------------------------------------------------------
__device__ int g_isf32;
__device__ __attribute__((aligned(256))) unsigned short g_qb [ELEMS]; // [bh][n][d] bf16 (pre-scaled)
__device__ __attribute__((aligned(256))) unsigned short g_kb [ELEMS]; // [bh][n][d] bf16
__device__ __attribute__((aligned(256))) unsigned short g_tA [ELEMS]; // [bh][d][n] bf16
__device__ __attribute__((aligned(256))) unsigned short g_tB [ELEMS]; // [bh][d][n] bf16
__device__ __attribute__((aligned(256))) float          g_acc[ELEMS]; // [b][n][D] f32
__device__ __attribute__((aligned(256))) unsigned short g_wt [4*DD*DD]; // W^T bf16 [mat][n][k]
__device__ __attribute__((aligned(256))) float g_bias[4*DD];
__device__ __attribute__((aligned(256))) float g_cf[HH*4];
__device__ __attribute__((aligned(256))) float g_invl[BB*HH*NN];      // cached 1/rowsum (pass 1)

__device__ __forceinline__ float b2f(unsigned short u) {
    union { unsigned int i; float f; } c; c.i = ((unsigned int)u) << 16; return c.f;
}
__device__ __forceinline__ unsigned short f2b(float f) {           // safe path
    bf16 h = __float2bfloat16(f);
    return *reinterpret_cast<unsigned short*>(&h);
}
// pack two f32 -> one u32 of two bf16 (RNE).  gfx950 has a 1-instr pk cvt.
#if __has_builtin(__builtin_amdgcn_cvt_pk_bf16_f32)
typedef __attribute__((ext_vector_type(2))) __bf16 bf16x2t;
__device__ __forceinline__ unsigned int pk2(float a, float b) {
    union { bf16x2t v; unsigned int u; } c;
    c.v = __builtin_amdgcn_cvt_pk_bf16_f32(a, b);
    return c.u;
}
#else
__device__ __forceinline__ unsigned int pk2(float a, float b) {
    unsigned int ua = __float_as_uint(a), ub = __float_as_uint(b);
    ua = (ua + 0x7FFFu + ((ua >> 16) & 1u)) >> 16;
    ub = (ub + 0x7FFFu + ((ub >> 16) & 1u)) & 0xFFFF0000u;
    return ua | ub;
}
#endif
__device__ __forceinline__ float ldin(const void* p, int i, int f32m) {
    return f32m ? ((const float*)p)[i] : b2f(((const unsigned short*)p)[i]);
}

// ---------------------------------------------------------------------------
// Kernel 0: dtype probe (unchanged — verified rounds 4-10).
// ---------------------------------------------------------------------------
__global__ __launch_bounds__(256) void probe_kernel(const void* __restrict__ x)
{
    __shared__ int cnt;
    if (threadIdx.x == 0) cnt = 0;
    __syncthreads();
    const unsigned short* u = (const unsigned short*)x;
    int w = 0;
    for (int i = threadIdx.x; i < 1024; i += 256) {
        const int e = (u[2 * i] >> 7) & 0xFF;
        if (e < 100 || e > 140) ++w;
    }
    atomicAdd(&cnt, w);
    __syncthreads();
    if (threadIdx.x == 0) g_isf32 = (cnt > 300) ? 1 : 0;
}

// ---------------------------------------------------------------------------
// Prep: transpose W[k][n] -> g_wt[mat][n][k] bf16; block(0,0) also preps
// biases + coeffs to f32.
// ---------------------------------------------------------------------------
__global__ __launch_bounds__(256) void prep_w_kernel(
    const void* W0, const void* W1, const void* W2, const void* W3,
    const void* bq, const void* bk, const void* bv, const void* bo,
    const void* coeffs)
{
    const int f32m = g_isf32;
    __shared__ unsigned short tile[64][65];
    const int mat = blockIdx.y;
    const void* W = (mat == 0) ? W0 : (mat == 1) ? W1 : (mat == 2) ? W2 : W3;
    const int k0 = (blockIdx.x >> 2) * 64;
    const int n0 = (blockIdx.x & 3) * 64;
    const int t  = threadIdx.x;

    if (blockIdx.x == 0 && blockIdx.y == 0) {
        g_bias[0 * DD + t] = ldin(bq, t, f32m);
        g_bias[1 * DD + t] = ldin(bk, t, f32m);
        g_bias[2 * DD + t] = ldin(bv, t, f32m);
        g_bias[3 * DD + t] = ldin(bo, t, f32m);
        if (t < 32) g_cf[t] = ldin(coeffs, t, f32m);
    }

    #pragma unroll
    for (int it = 0; it < 16; ++it) {
        const int flat = it * 256 + t;
        const int i = flat >> 6, j = flat & 63;
        tile[j][i] = f2b(ldin(W, (k0 + i) * DD + n0 + j, f32m));
    }
    __syncthreads();
    unsigned short* wt = g_wt + mat * DD * DD;
    #pragma unroll
    for (int it = 0; it < 16; ++it) {
        const int flat = it * 256 + t;
        const int nl = flat >> 6, kl = flat & 63;
        wt[(n0 + nl) * DD + k0 + kl] = tile[nl][kl];
    }
}

// ---------------------------------------------------------------------------
// Kernel 1: QKV projection GEMM (unchanged from r10).
// ---------------------------------------------------------------------------
__global__ __launch_bounds__(256) void qkv_gemm_kernel(const void* __restrict__ x)
{
    __shared__ unsigned short xs[64 * 32];
    __shared__ unsigned short wl[64 * 32];
    const int f32m = g_isf32;
    const int t  = threadIdx.x;
    const int w  = t >> 6, l = t & 63, lg = l >> 4, ln = l & 15;
    const int r0 = blockIdx.x * 64;
    const int n0 = blockIdx.y * 64;
    const int mat = blockIdx.z;
    const unsigned short* wt = g_wt + mat * DD * DD;
    const int sr = t >> 2, sc = (t & 3) * 8;

    f32x4 acc[4] = {{0,0,0,0},{0,0,0,0},{0,0,0,0},{0,0,0,0}};

    for (int kc = 0; kc < DD; kc += 32) {
        __syncthreads();
        if (f32m) {
            const float* src = (const float*)x + (size_t)(r0 + sr) * DD + kc + sc;
            const float4 a = *(const float4*)src;
            const float4 b = *(const float4*)(src + 4);
            union { uint4 v; unsigned short s[8]; } o;
            o.s[0]=f2b(a.x); o.s[1]=f2b(a.y); o.s[2]=f2b(a.z); o.s[3]=f2b(a.w);
            o.s[4]=f2b(b.x); o.s[5]=f2b(b.y); o.s[6]=f2b(b.z); o.s[7]=f2b(b.w);
            *(uint4*)(xs + sr * 32 + sc) = o.v;
        } else {
            *(uint4*)(xs + sr * 32 + sc) =
                *(const uint4*)((const unsigned short*)x + (size_t)(r0 + sr) * DD + kc + sc);
        }
        *(uint4*)(wl + sr * 32 + sc) =
            *(const uint4*)(wt + (size_t)(n0 + sr) * DD + kc + sc);
        __syncthreads();
        const short8 af = *(const short8*)(xs + (w * 16 + ln) * 32 + lg * 8);
        #pragma unroll
        for (int s = 0; s < 4; ++s) {
            const short8 bfr = *(const short8*)(wl + (s * 16 + ln) * 32 + lg * 8);
            acc[s] = __builtin_amdgcn_mfma_f32_16x16x32_bf16(af, bfr, acc[s], 0, 0, 0);
        }
    }

    const float QS = 0.17677669529663687f * 1.4426950408889634f; // scale*log2e
    #pragma unroll
    for (int s = 0; s < 4; ++s) {
        const int j = n0 + s * 16 + ln;
        const float bias = g_bias[mat * DD + j];
        const int h = j >> 5, dd = j & 31;
        #pragma unroll
        for (int r = 0; r < 4; ++r) {
            const int rn = r0 + w * 16 + lg * 4 + r;
            const int b = rn >> 11, n = rn & (NN - 1);
            const int bh = b * HH + h;
            const float val = acc[s][r] + bias;
            if (mat == 0) {
                g_qb[((size_t)bh * NN + n) * HD + dd] = f2b(val * QS);
            } else if (mat == 1) {
                g_kb[((size_t)bh * NN + n) * HD + dd] = f2b(val);
            } else {
                g_tA[((size_t)bh * HD + dd) * NN + n] = f2b(val);
                g_acc[(size_t)rn * DD + j] = g_cf[h * 4] * val;
            }
        }
    }
}

// ---------------------------------------------------------------------------
// Kernel 2 (r16): attention pass.  r15 loop body (verified bit-exact path)
// with q-tile 32 and NO register cap.  Rationale: r15 proved FETCH 4x lower
// with identical time -> not memory-traffic bound; per-SIMD issue arithmetic
// shows both pipes <20% busy -> exposed dependent latency, needs more wave
// slots.  Old shape: grid 1024 (4 blk/CU) AND LDS 34.8KB both capped at
// 4 waves/SIMD.  New: q-tile 32 -> grid 2048 (8 blk/CU), LDS 17.4KB (8
// blk/CU fits), natural VGPR ~64 (8 waves/SIMD allowed) -> 2x TLP.
// r13's q-tile-32 failure was its launch_bounds(256,6)/VGPR=36 cap, not the
// tile size — no cap here.
// XCD swizzle kept (L2-resident K/T, verified FETCH=unique).  KIND
// specialization kept: KIND=0 caches 1/rowsum; 1/2 skip row-sum work;
// 2 skips dead tout store.
// ---------------------------------------------------------------------------
template<int KIND>
__global__ __launch_bounds__(256) void attn_pass_kernel(const int kidx, const int dir)
{
    __shared__ float osh[4][32][33];   // [wave][q][d] (+1 pad) ~16.9 KB
    __shared__ float lsh[4][32];

    const unsigned short* __restrict__ tin  = dir ? g_tB : g_tA;
    unsigned short*       __restrict__ tout = dir ? g_tA : g_tB;

    const int tid = threadIdx.x;
    const int w   = tid >> 6;
    const int l   = tid & 63;
    const int lg  = l >> 4;
    const int ln  = l & 15;

    // XCD swizzle: bi%8 selects XCD (round-robin); each XCD gets 4 bh,
    // all 64 q-tiles of a bh stay on one XCD.
    const int bi = blockIdx.x;                 // grid 2048
    const int bh = (bi & 7) * 4 + ((bi >> 3) & 3);   // b*H + h
    const int qt = bi >> 5;                    // 0..63
    const int h  = bh & (HH - 1);
    const int b  = bh >> 3;
    const int q0 = qt * 32;

    short8 qf[2];
    #pragma unroll
    for (int qi = 0; qi < 2; ++qi)
        qf[qi] = *(const short8*)(g_qb +
            ((size_t)bh * NN + q0 + qi * 16 + ln) * HD + lg * 8);

    const unsigned short* kb = g_kb + (size_t)bh * NN * HD;
    const unsigned short* tb = tin  + (size_t)bh * HD * NN;

    f32x4 oacc[2][2];
    #pragma unroll
    for (int qi = 0; qi < 2; ++qi) { oacc[qi][0] = (f32x4){0,0,0,0}; oacc[qi][1] = (f32x4){0,0,0,0}; }
    float lsum[2] = {0.f, 0.f};
    const f32x4 zero = {0.f, 0.f, 0.f, 0.f};

    for (int it = 0; it < 16; ++it) {
        const int k0 = it * 128 + w * 32;   // this wave's 32-key strip
        const short8 kf0 = *(const short8*)(kb + (size_t)(k0 + ln) * HD + lg * 8);
        const short8 kf1 = *(const short8*)(kb + (size_t)(k0 + 16 + ln) * HD + lg * 8);

#if __has_builtin(__builtin_amdgcn_mfma_f32_16x16x16bf16_1k)
        // T^T A-frags for K=16 PV: [c=key-chunk][hf=dim-half], 8B each
        short4v tf[2][2];
        #pragma unroll
        for (int c = 0; c < 2; ++c)
            #pragma unroll
            for (int hf = 0; hf < 2; ++hf)
                tf[c][hf] = *(const short4v*)(tb +
                    (size_t)(hf * 16 + ln) * NN + k0 + c * 16 + lg * 4);

        #pragma unroll
        for (int qi = 0; qi < 2; ++qi) {
            f32x4 s0 = __builtin_amdgcn_mfma_f32_16x16x32_bf16(kf0, qf[qi], zero, 0, 0, 0);
            f32x4 s1 = __builtin_amdgcn_mfma_f32_16x16x32_bf16(kf1, qf[qi], zero, 0, 0, 0);
            float p[8];
            #pragma unroll
            for (int r = 0; r < 4; ++r) {
                p[r]     = __builtin_amdgcn_exp2f(s0[r]);
                p[4 + r] = __builtin_amdgcn_exp2f(s1[r]);
                if (KIND == 0) lsum[qi] += p[r] + p[4 + r];
            }
            union { unsigned int u[2]; short4v s; } pb0, pb1;
            pb0.u[0] = pk2(p[0], p[1]); pb0.u[1] = pk2(p[2], p[3]);
            pb1.u[0] = pk2(p[4], p[5]); pb1.u[1] = pk2(p[6], p[7]);
            oacc[qi][0] = __builtin_amdgcn_mfma_f32_16x16x16bf16_1k(tf[0][0], pb0.s, oacc[qi][0], 0, 0, 0);
            oacc[qi][1] = __builtin_amdgcn_mfma_f32_16x16x16bf16_1k(tf[0][1], pb0.s, oacc[qi][1], 0, 0, 0);
            oacc[qi][0] = __builtin_amdgcn_mfma_f32_16x16x16bf16_1k(tf[1][0], pb1.s, oacc[qi][0], 0, 0, 0);
            oacc[qi][1] = __builtin_amdgcn_mfma_f32_16x16x16bf16_1k(tf[1][1], pb1.s, oacc[qi][1], 0, 0, 0);
        }
#else
        // fallback: r10's verified shuffle-transpose path (K=32 PV)
        const short8 tf0 = *(const short8*)(tb + (size_t)ln * NN + k0 + lg * 8);
        const short8 tf1 = *(const short8*)(tb + (size_t)(ln + 16) * NN + k0 + lg * 8);
        #pragma unroll
        for (int qi = 0; qi < 2; ++qi) {
            f32x4 s0 = __builtin_amdgcn_mfma_f32_16x16x32_bf16(kf0, qf[qi], zero, 0, 0, 0);
            f32x4 s1 = __builtin_amdgcn_mfma_f32_16x16x32_bf16(kf1, qf[qi], zero, 0, 0, 0);
            float p[8];
            #pragma unroll
            for (int r = 0; r < 4; ++r) {
                p[r]     = __builtin_amdgcn_exp2f(s0[r]);
                p[4 + r] = __builtin_amdgcn_exp2f(s1[r]);
                if (KIND == 0) lsum[qi] += p[r] + p[4 + r];
            }
            const unsigned int pk0 = pk2(p[0], p[1]);
            const unsigned int pk1 = pk2(p[2], p[3]);
            const unsigned int pk2v = pk2(p[4], p[5]);
            const unsigned int pk3 = pk2(p[6], p[7]);
            int bi2[4];
            #pragma unroll
            for (int j = 0; j < 4; ++j) {
                const int srcLane = (((2 * lg + (j >> 1)) & 3) << 4) + ln;
                const int lo = __shfl((j & 1) ? (int)pk1 : (int)pk0, srcLane, 64);
                const int hi = __shfl((j & 1) ? (int)pk3 : (int)pk2v, srcLane, 64);
                bi2[j] = (lg < 2) ? lo : hi;
            }
            union { int i[4]; short8 s; } pf;
            pf.i[0] = bi2[0]; pf.i[1] = bi2[1]; pf.i[2] = bi2[2]; pf.i[3] = bi2[3];
            oacc[qi][0] = __builtin_amdgcn_mfma_f32_16x16x32_bf16(tf0, pf.s, oacc[qi][0], 0, 0, 0);
            oacc[qi][1] = __builtin_amdgcn_mfma_f32_16x16x32_bf16(tf1, pf.s, oacc[qi][1], 0, 0, 0);
        }
#endif
    }

    // lsum: reduce across lg groups (lanes sharing ln) — pass 1 only
    if (KIND == 0) {
        #pragma unroll
        for (int qi = 0; qi < 2; ++qi) {
            lsum[qi] += __shfl_xor(lsum[qi], 16, 64);
            lsum[qi] += __shfl_xor(lsum[qi], 32, 64);
        }
        if (lg == 0) {
            #pragma unroll
            for (int qi = 0; qi < 2; ++qi) lsh[w][qi * 16 + ln] = lsum[qi];
        }
    }

    // store O^T wave-partials: row q = qi*16+ln, col d = hf*16+lg*4+r
    #pragma unroll
    for (int qi = 0; qi < 2; ++qi)
        #pragma unroll
        for (int hf = 0; hf < 2; ++hf)
            #pragma unroll
            for (int r = 0; r < 4; ++r)
                osh[w][qi * 16 + ln][hf * 16 + lg * 4 + r] = oacc[qi][hf][r];
    __syncthreads();

    // combine 4 wave-partials; thread t: q = t&31, dims (t>>5)*4 ..+3
    {
        const int q  = tid & 31;
        const int db = (tid >> 5) * 4;
        float invl;
        if (KIND == 0) {
            invl = 1.0f / (lsh[0][q] + lsh[1][q] + lsh[2][q] + lsh[3][q]);
            if (db == 0) g_invl[(size_t)bh * NN + q0 + q] = invl;
        } else {
            invl = g_invl[(size_t)bh * NN + q0 + q];
        }
        const float ck = g_cf[h * 4 + kidx];
        #pragma unroll
        for (int dd = 0; dd < 4; ++dd) {
            const int d = db + dd;
            const float val = (osh[0][q][d] + osh[1][q][d] +
                               osh[2][q][d] + osh[3][q][d]) * invl;
            if (KIND != 2)
                tout[((size_t)bh * HD + d) * NN + q0 + q] = f2b(val);
            float* ga = g_acc + ((size_t)(b * NN + q0 + q)) * DD + h * HD + d;
            *ga += ck * val;
        }
    }
}

// ---------------------------------------------------------------------------
// Kernel 3: output projection GEMM (unchanged).
// ---------------------------------------------------------------------------
__global__ __launch_bounds__(256) void out_gemm_kernel(void* __restrict__ out)
{
    __shared__ unsigned short xs[64 * 32];
    __shared__ unsigned short wl[64 * 32];
    const int f32m = g_isf32;
    const int t  = threadIdx.x;
    const int w  = t >> 6, l = t & 63, lg = l >> 4, ln = l & 15;
    const int r0 = blockIdx.x * 64;
    const int n0 = blockIdx.y * 64;
    const unsigned short* wt = g_wt + 3 * DD * DD;
    const int sr = t >> 2, sc = (t & 3) * 8;

    f32x4 acc[4] = {{0,0,0,0},{0,0,0,0},{0,0,0,0},{0,0,0,0}};

    for (int kc = 0; kc < DD; kc += 32) {
        __syncthreads();
        {
            const float* src = g_acc + (size_t)(r0 + sr) * DD + kc + sc;
            const float4 a = *(const float4*)src;
            const float4 b = *(const float4*)(src + 4);
            union { uint4 v; unsigned short s[8]; } o;
            o.s[0]=f2b(a.x); o.s[1]=f2b(a.y); o.s[2]=f2b(a.z); o.s[3]=f2b(a.w);
            o.s[4]=f2b(b.x); o.s[5]=f2b(b.y); o.s[6]=f2b(b.z); o.s[7]=f2b(b.w);
            *(uint4*)(xs + sr * 32 + sc) = o.v;
        }
        *(uint4*)(wl + sr * 32 + sc) =
            *(const uint4*)(wt + (size_t)(n0 + sr) * DD + kc + sc);
        __syncthreads();
        const short8 af = *(const short8*)(xs + (w * 16 + ln) * 32 + lg * 8);
        #pragma unroll
        for (int s = 0; s < 4; ++s) {
            const short8 bfr = *(const short8*)(wl + (s * 16 + ln) * 32 + lg * 8);
            acc[s] = __builtin_amdgcn_mfma_f32_16x16x32_bf16(af, bfr, acc[s], 0, 0, 0);
        }
    }

    #pragma unroll
    for (int s = 0; s < 4; ++s) {
        const int j = n0 + s * 16 + ln;
        const float bias = g_bias[3 * DD + j];
        #pragma unroll
        for (int r = 0; r < 4; ++r) {
            const int rn = r0 + w * 16 + lg * 4 + r;
            const float val = acc[s][r] + bias;
            if (f32m) ((float*)out)[(size_t)rn * DD + j] = val;
            else      ((bf16*)out)[(size_t)rn * DD + j] = __float2bfloat16(val);
        }
    }
}

// ---------------------------------------------------------------------------
extern "C" void kernel_launch(void* const* d_in, const int* in_sizes, int n_in,
                              void* d_out, int out_size, void* d_ws, size_t ws_size,
                              hipStream_t stream)
{
    const void* x      = d_in[0];
    const void* Wq     = d_in[1];
    const void* bq     = d_in[2];
    const void* Wk     = d_in[3];
    const void* bk     = d_in[4];
    const void* Wv     = d_in[5];
    const void* bv     = d_in[6];
    const void* Wo     = d_in[7];
    const void* bo     = d_in[8];
    const void* coeffs = d_in[9];
    (void)d_ws; (void)ws_size; (void)in_sizes; (void)n_in; (void)out_size;

    probe_kernel<<<1, 256, 0, stream>>>(x);

    prep_w_kernel<<<dim3(16, 4), 256, 0, stream>>>(Wq, Wk, Wv, Wo,
                                                   bq, bk, bv, bo, coeffs);

    qkv_gemm_kernel<<<dim3(128, 4, 3), 256, 0, stream>>>(x);

    const int agrid = (BB * HH) * (NN / 32);   // 32 * 64 = 2048 blocks
    attn_pass_kernel<0><<<agrid, 256, 0, stream>>>(1, 0); // tA -> tB, caches invl
    attn_pass_kernel<1><<<agrid, 256, 0, stream>>>(2, 1); // tB -> tA, uses invl
    attn_pass_kernel<2><<<agrid, 256, 0, stream>>>(3, 0); // tA -> (acc only)

    out_gemm_kernel<<<dim3(128, 4), 256, 0, stream>>>(d_out);
}

// Round 6
// 228.522 us; speedup vs baseline: 1.4937x; 1.4937x over previous
//
#include <hip/hip_runtime.h>
#include <hip/hip_bf16.h>

typedef __hip_bfloat16 bf16;
typedef __attribute__((ext_vector_type(8))) short short8;   // 8 bf16 = 4 VGPRs
typedef __attribute__((ext_vector_type(4))) short short4v;  // 4 bf16 = 2 VGPRs
typedef __attribute__((ext_vector_type(4))) float f32x4;    // MFMA C/D

#define BB 4
#define NN 2048
#define DD 256
#define HH 8
#define HD 32
#define BN (BB*NN)          // 8192
#define ELEMS (BN*DD)       // 2097152

// ---------------------------------------------------------------------------
// Scratch in module .bss (~25 MB).
// ---------------------------------------------------------------------------
__device__ int g_isf32;
__device__ __attribute__((aligned(256))) unsigned short g_qb [ELEMS]; // [bh][n][d] bf16 (pre-scaled)
__device__ __attribute__((aligned(256))) unsigned short g_kb [ELEMS]; // [bh][n][d] bf16
__device__ __attribute__((aligned(256))) unsigned short g_tA [ELEMS]; // [bh][d][n] bf16
__device__ __attribute__((aligned(256))) unsigned short g_tB [ELEMS]; // [bh][d][n] bf16
__device__ __attribute__((aligned(256))) float          g_acc[ELEMS]; // [b][n][D] f32
__device__ __attribute__((aligned(256))) unsigned short g_wt [4*DD*DD]; // W^T bf16 [mat][n][k]
__device__ __attribute__((aligned(256))) float g_bias[4*DD];
__device__ __attribute__((aligned(256))) float g_cf[HH*4];
__device__ __attribute__((aligned(256))) float g_invl[BB*HH*NN];      // cached 1/rowsum (pass 1)

__device__ __forceinline__ float b2f(unsigned short u) {
    union { unsigned int i; float f; } c; c.i = ((unsigned int)u) << 16; return c.f;
}
__device__ __forceinline__ unsigned short f2b(float f) {           // safe path
    bf16 h = __float2bfloat16(f);
    return *reinterpret_cast<unsigned short*>(&h);
}
// pack two f32 -> one u32 of two bf16 (RNE).  gfx950 has a 1-instr pk cvt.
#if __has_builtin(__builtin_amdgcn_cvt_pk_bf16_f32)
typedef __attribute__((ext_vector_type(2))) __bf16 bf16x2t;
__device__ __forceinline__ unsigned int pk2(float a, float b) {
    union { bf16x2t v; unsigned int u; } c;
    c.v = __builtin_amdgcn_cvt_pk_bf16_f32(a, b);
    return c.u;
}
#else
__device__ __forceinline__ unsigned int pk2(float a, float b) {
    unsigned int ua = __float_as_uint(a), ub = __float_as_uint(b);
    ua = (ua + 0x7FFFu + ((ua >> 16) & 1u)) >> 16;
    ub = (ub + 0x7FFFu + ((ub >> 16) & 1u)) & 0xFFFF0000u;
    return ua | ub;
}
#endif
__device__ __forceinline__ float ldin(const void* p, int i, int f32m) {
    return f32m ? ((const float*)p)[i] : b2f(((const unsigned short*)p)[i]);
}

// ---------------------------------------------------------------------------
// Kernel 0: dtype probe (unchanged — verified rounds 4-10).
// ---------------------------------------------------------------------------
__global__ __launch_bounds__(256) void probe_kernel(const void* __restrict__ x)
{
    __shared__ int cnt;
    if (threadIdx.x == 0) cnt = 0;
    __syncthreads();
    const unsigned short* u = (const unsigned short*)x;
    int w = 0;
    for (int i = threadIdx.x; i < 1024; i += 256) {
        const int e = (u[2 * i] >> 7) & 0xFF;
        if (e < 100 || e > 140) ++w;
    }
    atomicAdd(&cnt, w);
    __syncthreads();
    if (threadIdx.x == 0) g_isf32 = (cnt > 300) ? 1 : 0;
}

// ---------------------------------------------------------------------------
// Prep: transpose W[k][n] -> g_wt[mat][n][k] bf16; block(0,0) also preps
// biases + coeffs to f32.
// ---------------------------------------------------------------------------
__global__ __launch_bounds__(256) void prep_w_kernel(
    const void* W0, const void* W1, const void* W2, const void* W3,
    const void* bq, const void* bk, const void* bv, const void* bo,
    const void* coeffs)
{
    const int f32m = g_isf32;
    __shared__ unsigned short tile[64][65];
    const int mat = blockIdx.y;
    const void* W = (mat == 0) ? W0 : (mat == 1) ? W1 : (mat == 2) ? W2 : W3;
    const int k0 = (blockIdx.x >> 2) * 64;
    const int n0 = (blockIdx.x & 3) * 64;
    const int t  = threadIdx.x;

    if (blockIdx.x == 0 && blockIdx.y == 0) {
        g_bias[0 * DD + t] = ldin(bq, t, f32m);
        g_bias[1 * DD + t] = ldin(bk, t, f32m);
        g_bias[2 * DD + t] = ldin(bv, t, f32m);
        g_bias[3 * DD + t] = ldin(bo, t, f32m);
        if (t < 32) g_cf[t] = ldin(coeffs, t, f32m);
    }

    #pragma unroll
    for (int it = 0; it < 16; ++it) {
        const int flat = it * 256 + t;
        const int i = flat >> 6, j = flat & 63;
        tile[j][i] = f2b(ldin(W, (k0 + i) * DD + n0 + j, f32m));
    }
    __syncthreads();
    unsigned short* wt = g_wt + mat * DD * DD;
    #pragma unroll
    for (int it = 0; it < 16; ++it) {
        const int flat = it * 256 + t;
        const int nl = flat >> 6, kl = flat & 63;
        wt[(n0 + nl) * DD + k0 + kl] = tile[nl][kl];
    }
}

// ---------------------------------------------------------------------------
// Kernel 1: QKV projection GEMM (unchanged from r10).
// ---------------------------------------------------------------------------
__global__ __launch_bounds__(256) void qkv_gemm_kernel(const void* __restrict__ x)
{
    __shared__ unsigned short xs[64 * 32];
    __shared__ unsigned short wl[64 * 32];
    const int f32m = g_isf32;
    const int t  = threadIdx.x;
    const int w  = t >> 6, l = t & 63, lg = l >> 4, ln = l & 15;
    const int r0 = blockIdx.x * 64;
    const int n0 = blockIdx.y * 64;
    const int mat = blockIdx.z;
    const unsigned short* wt = g_wt + mat * DD * DD;
    const int sr = t >> 2, sc = (t & 3) * 8;

    f32x4 acc[4] = {{0,0,0,0},{0,0,0,0},{0,0,0,0},{0,0,0,0}};

    for (int kc = 0; kc < DD; kc += 32) {
        __syncthreads();
        if (f32m) {
            const float* src = (const float*)x + (size_t)(r0 + sr) * DD + kc + sc;
            const float4 a = *(const float4*)src;
            const float4 b = *(const float4*)(src + 4);
            union { uint4 v; unsigned short s[8]; } o;
            o.s[0]=f2b(a.x); o.s[1]=f2b(a.y); o.s[2]=f2b(a.z); o.s[3]=f2b(a.w);
            o.s[4]=f2b(b.x); o.s[5]=f2b(b.y); o.s[6]=f2b(b.z); o.s[7]=f2b(b.w);
            *(uint4*)(xs + sr * 32 + sc) = o.v;
        } else {
            *(uint4*)(xs + sr * 32 + sc) =
                *(const uint4*)((const unsigned short*)x + (size_t)(r0 + sr) * DD + kc + sc);
        }
        *(uint4*)(wl + sr * 32 + sc) =
            *(const uint4*)(wt + (size_t)(n0 + sr) * DD + kc + sc);
        __syncthreads();
        const short8 af = *(const short8*)(xs + (w * 16 + ln) * 32 + lg * 8);
        #pragma unroll
        for (int s = 0; s < 4; ++s) {
            const short8 bfr = *(const short8*)(wl + (s * 16 + ln) * 32 + lg * 8);
            acc[s] = __builtin_amdgcn_mfma_f32_16x16x32_bf16(af, bfr, acc[s], 0, 0, 0);
        }
    }

    const float QS = 0.17677669529663687f * 1.4426950408889634f; // scale*log2e
    #pragma unroll
    for (int s = 0; s < 4; ++s) {
        const int j = n0 + s * 16 + ln;
        const float bias = g_bias[mat * DD + j];
        const int h = j >> 5, dd = j & 31;
        #pragma unroll
        for (int r = 0; r < 4; ++r) {
            const int rn = r0 + w * 16 + lg * 4 + r;
            const int b = rn >> 11, n = rn & (NN - 1);
            const int bh = b * HH + h;
            const float val = acc[s][r] + bias;
            if (mat == 0) {
                g_qb[((size_t)bh * NN + n) * HD + dd] = f2b(val * QS);
            } else if (mat == 1) {
                g_kb[((size_t)bh * NN + n) * HD + dd] = f2b(val);
            } else {
                g_tA[((size_t)bh * HD + dd) * NN + n] = f2b(val);
                g_acc[(size_t)rn * DD + j] = g_cf[h * 4] * val;
            }
        }
    }
}

// ---------------------------------------------------------------------------
// Kernel 2 (r17): attention pass, q-tile 128.
// Evidence ladder (r11..r16): time tracks TOTAL fragment-load instructions
// (2x loads -> 1.74x time at ANY occupancy/VGPR), insensitive to L2-vs-HBM
// (r15 swizzle: FETCH 4x down, time flat) -> vector-gather (TA line)
// throughput bound.  Fix: q-tile 64 -> 128: the same 6 loads/it/wave now
// feed 48 MFMAs instead of 24 -> grid-wide fragment loads HALVE.
// Registers: only the persistent set grows (qf[8]=32, oacc[8][2]=64,
// ~145 total) — no min-wave launch_bounds (r14's spill was its (256,4)
// 128-VGPR cap + transient doubling; here transients are unchanged).
// LDS <=64KB via wave-pair combine: waves 0/1 write osh[2][128][33],
// waves 2/3 += into it, epilogue sums 2 partials (35.8 KB total).
// XCD swizzle kept (grid 512 = 32 bh x 16 qt).  KIND specialization kept.
// ---------------------------------------------------------------------------
template<int KIND>
__global__ __launch_bounds__(256) void attn_pass_kernel(const int kidx, const int dir)
{
    __shared__ float osh[2][128][33];   // wave-pair partials (+1 pad) 33.8 KB
    __shared__ float lsh[4][128];

    const unsigned short* __restrict__ tin  = dir ? g_tB : g_tA;
    unsigned short*       __restrict__ tout = dir ? g_tA : g_tB;

    const int tid = threadIdx.x;
    const int w   = tid >> 6;
    const int l   = tid & 63;
    const int lg  = l >> 4;
    const int ln  = l & 15;

    // XCD swizzle: bi%8 selects XCD; each XCD gets 4 bh, all 16 q-tiles of
    // a bh stay on one XCD.
    const int bi = blockIdx.x;                 // grid 512
    const int bh = (bi & 7) * 4 + ((bi >> 3) & 3);   // b*H + h
    const int qt = bi >> 5;                    // 0..15
    const int h  = bh & (HH - 1);
    const int b  = bh >> 3;
    const int q0 = qt * 128;

    short8 qf[8];
    #pragma unroll
    for (int qi = 0; qi < 8; ++qi)
        qf[qi] = *(const short8*)(g_qb +
            ((size_t)bh * NN + q0 + qi * 16 + ln) * HD + lg * 8);

    const unsigned short* kb = g_kb + (size_t)bh * NN * HD;
    const unsigned short* tb = tin  + (size_t)bh * HD * NN;

    f32x4 oacc[8][2];
    #pragma unroll
    for (int qi = 0; qi < 8; ++qi) { oacc[qi][0] = (f32x4){0,0,0,0}; oacc[qi][1] = (f32x4){0,0,0,0}; }
    float lsum[8] = {0.f, 0.f, 0.f, 0.f, 0.f, 0.f, 0.f, 0.f};
    const f32x4 zero = {0.f, 0.f, 0.f, 0.f};

    for (int it = 0; it < 16; ++it) {
        const int k0 = it * 128 + w * 32;   // this wave's 32-key strip
        const short8 kf0 = *(const short8*)(kb + (size_t)(k0 + ln) * HD + lg * 8);
        const short8 kf1 = *(const short8*)(kb + (size_t)(k0 + 16 + ln) * HD + lg * 8);

#if __has_builtin(__builtin_amdgcn_mfma_f32_16x16x16bf16_1k)
        // T^T A-frags for K=16 PV: [c=key-chunk][hf=dim-half], 8B each
        short4v tf[2][2];
        #pragma unroll
        for (int c = 0; c < 2; ++c)
            #pragma unroll
            for (int hf = 0; hf < 2; ++hf)
                tf[c][hf] = *(const short4v*)(tb +
                    (size_t)(hf * 16 + ln) * NN + k0 + c * 16 + lg * 4);

        #pragma unroll
        for (int qi = 0; qi < 8; ++qi) {
            f32x4 s0 = __builtin_amdgcn_mfma_f32_16x16x32_bf16(kf0, qf[qi], zero, 0, 0, 0);
            f32x4 s1 = __builtin_amdgcn_mfma_f32_16x16x32_bf16(kf1, qf[qi], zero, 0, 0, 0);
            float p[8];
            #pragma unroll
            for (int r = 0; r < 4; ++r) {
                p[r]     = __builtin_amdgcn_exp2f(s0[r]);
                p[4 + r] = __builtin_amdgcn_exp2f(s1[r]);
                if (KIND == 0) lsum[qi] += p[r] + p[4 + r];
            }
            union { unsigned int u[2]; short4v s; } pb0, pb1;
            pb0.u[0] = pk2(p[0], p[1]); pb0.u[1] = pk2(p[2], p[3]);
            pb1.u[0] = pk2(p[4], p[5]); pb1.u[1] = pk2(p[6], p[7]);
            oacc[qi][0] = __builtin_amdgcn_mfma_f32_16x16x16bf16_1k(tf[0][0], pb0.s, oacc[qi][0], 0, 0, 0);
            oacc[qi][1] = __builtin_amdgcn_mfma_f32_16x16x16bf16_1k(tf[0][1], pb0.s, oacc[qi][1], 0, 0, 0);
            oacc[qi][0] = __builtin_amdgcn_mfma_f32_16x16x16bf16_1k(tf[1][0], pb1.s, oacc[qi][0], 0, 0, 0);
            oacc[qi][1] = __builtin_amdgcn_mfma_f32_16x16x16bf16_1k(tf[1][1], pb1.s, oacc[qi][1], 0, 0, 0);
        }
#else
        // fallback: r10's verified shuffle-transpose path (K=32 PV)
        const short8 tf0 = *(const short8*)(tb + (size_t)ln * NN + k0 + lg * 8);
        const short8 tf1 = *(const short8*)(tb + (size_t)(ln + 16) * NN + k0 + lg * 8);
        #pragma unroll
        for (int qi = 0; qi < 8; ++qi) {
            f32x4 s0 = __builtin_amdgcn_mfma_f32_16x16x32_bf16(kf0, qf[qi], zero, 0, 0, 0);
            f32x4 s1 = __builtin_amdgcn_mfma_f32_16x16x32_bf16(kf1, qf[qi], zero, 0, 0, 0);
            float p[8];
            #pragma unroll
            for (int r = 0; r < 4; ++r) {
                p[r]     = __builtin_amdgcn_exp2f(s0[r]);
                p[4 + r] = __builtin_amdgcn_exp2f(s1[r]);
                if (KIND == 0) lsum[qi] += p[r] + p[4 + r];
            }
            const unsigned int pk0 = pk2(p[0], p[1]);
            const unsigned int pk1 = pk2(p[2], p[3]);
            const unsigned int pk2v = pk2(p[4], p[5]);
            const unsigned int pk3 = pk2(p[6], p[7]);
            int bi2[4];
            #pragma unroll
            for (int j = 0; j < 4; ++j) {
                const int srcLane = (((2 * lg + (j >> 1)) & 3) << 4) + ln;
                const int lo = __shfl((j & 1) ? (int)pk1 : (int)pk0, srcLane, 64);
                const int hi = __shfl((j & 1) ? (int)pk3 : (int)pk2v, srcLane, 64);
                bi2[j] = (lg < 2) ? lo : hi;
            }
            union { int i[4]; short8 s; } pf;
            pf.i[0] = bi2[0]; pf.i[1] = bi2[1]; pf.i[2] = bi2[2]; pf.i[3] = bi2[3];
            oacc[qi][0] = __builtin_amdgcn_mfma_f32_16x16x32_bf16(tf0, pf.s, oacc[qi][0], 0, 0, 0);
            oacc[qi][1] = __builtin_amdgcn_mfma_f32_16x16x32_bf16(tf1, pf.s, oacc[qi][1], 0, 0, 0);
        }
#endif
    }

    // lsum: reduce across lg groups (lanes sharing ln) — pass 1 only
    if (KIND == 0) {
        #pragma unroll
        for (int qi = 0; qi < 8; ++qi) {
            lsum[qi] += __shfl_xor(lsum[qi], 16, 64);
            lsum[qi] += __shfl_xor(lsum[qi], 32, 64);
        }
        if (lg == 0) {
            #pragma unroll
            for (int qi = 0; qi < 8; ++qi) lsh[w][qi * 16 + ln] = lsum[qi];
        }
    }

    // wave-pair combine: waves 0/1 write, waves 2/3 accumulate.
    // row q = qi*16+ln, col d = hf*16+lg*4+r
    if (w < 2) {
        #pragma unroll
        for (int qi = 0; qi < 8; ++qi)
            #pragma unroll
            for (int hf = 0; hf < 2; ++hf)
                #pragma unroll
                for (int r = 0; r < 4; ++r)
                    osh[w][qi * 16 + ln][hf * 16 + lg * 4 + r] = oacc[qi][hf][r];
    }
    __syncthreads();
    if (w >= 2) {
        #pragma unroll
        for (int qi = 0; qi < 8; ++qi)
            #pragma unroll
            for (int hf = 0; hf < 2; ++hf)
                #pragma unroll
                for (int r = 0; r < 4; ++r)
                    osh[w - 2][qi * 16 + ln][hf * 16 + lg * 4 + r] += oacc[qi][hf][r];
    }
    __syncthreads();

    // combine 2 partials; thread t: q = t&127, dims (t>>7)*16 ..+15
    {
        const int q  = tid & 127;
        const int db = (tid >> 7) * 16;
        float invl;
        if (KIND == 0) {
            invl = 1.0f / (lsh[0][q] + lsh[1][q] + lsh[2][q] + lsh[3][q]);
            if (db == 0) g_invl[(size_t)bh * NN + q0 + q] = invl;
        } else {
            invl = g_invl[(size_t)bh * NN + q0 + q];
        }
        const float ck = g_cf[h * 4 + kidx];
        #pragma unroll
        for (int dd = 0; dd < 16; ++dd) {
            const int d = db + dd;
            const float val = (osh[0][q][d] + osh[1][q][d]) * invl;
            if (KIND != 2)
                tout[((size_t)bh * HD + d) * NN + q0 + q] = f2b(val);
            float* ga = g_acc + ((size_t)(b * NN + q0 + q)) * DD + h * HD + d;
            *ga += ck * val;
        }
    }
}

// ---------------------------------------------------------------------------
// Kernel 3: output projection GEMM (unchanged).
// ---------------------------------------------------------------------------
__global__ __launch_bounds__(256) void out_gemm_kernel(void* __restrict__ out)
{
    __shared__ unsigned short xs[64 * 32];
    __shared__ unsigned short wl[64 * 32];
    const int f32m = g_isf32;
    const int t  = threadIdx.x;
    const int w  = t >> 6, l = t & 63, lg = l >> 4, ln = l & 15;
    const int r0 = blockIdx.x * 64;
    const int n0 = blockIdx.y * 64;
    const unsigned short* wt = g_wt + 3 * DD * DD;
    const int sr = t >> 2, sc = (t & 3) * 8;

    f32x4 acc[4] = {{0,0,0,0},{0,0,0,0},{0,0,0,0},{0,0,0,0}};

    for (int kc = 0; kc < DD; kc += 32) {
        __syncthreads();
        {
            const float* src = g_acc + (size_t)(r0 + sr) * DD + kc + sc;
            const float4 a = *(const float4*)src;
            const float4 b = *(const float4*)(src + 4);
            union { uint4 v; unsigned short s[8]; } o;
            o.s[0]=f2b(a.x); o.s[1]=f2b(a.y); o.s[2]=f2b(a.z); o.s[3]=f2b(a.w);
            o.s[4]=f2b(b.x); o.s[5]=f2b(b.y); o.s[6]=f2b(b.z); o.s[7]=f2b(b.w);
            *(uint4*)(xs + sr * 32 + sc) = o.v;
        }
        *(uint4*)(wl + sr * 32 + sc) =
            *(const uint4*)(wt + (size_t)(n0 + sr) * DD + kc + sc);
        __syncthreads();
        const short8 af = *(const short8*)(xs + (w * 16 + ln) * 32 + lg * 8);
        #pragma unroll
        for (int s = 0; s < 4; ++s) {
            const short8 bfr = *(const short8*)(wl + (s * 16 + ln) * 32 + lg * 8);
            acc[s] = __builtin_amdgcn_mfma_f32_16x16x32_bf16(af, bfr, acc[s], 0, 0, 0);
        }
    }

    #pragma unroll
    for (int s = 0; s < 4; ++s) {
        const int j = n0 + s * 16 + ln;
        const float bias = g_bias[3 * DD + j];
        #pragma unroll
        for (int r = 0; r < 4; ++r) {
            const int rn = r0 + w * 16 + lg * 4 + r;
            const float val = acc[s][r] + bias;
            if (f32m) ((float*)out)[(size_t)rn * DD + j] = val;
            else      ((bf16*)out)[(size_t)rn * DD + j] = __float2bfloat16(val);
        }
    }
}

// ---------------------------------------------------------------------------
extern "C" void kernel_launch(void* const* d_in, const int* in_sizes, int n_in,
                              void* d_out, int out_size, void* d_ws, size_t ws_size,
                              hipStream_t stream)
{
    const void* x      = d_in[0];
    const void* Wq     = d_in[1];
    const void* bq     = d_in[2];
    const void* Wk     = d_in[3];
    const void* bk     = d_in[4];
    const void* Wv     = d_in[5];
    const void* bv     = d_in[6];
    const void* Wo     = d_in[7];
    const void* bo     = d_in[8];
    const void* coeffs = d_in[9];
    (void)d_ws; (void)ws_size; (void)in_sizes; (void)n_in; (void)out_size;

    probe_kernel<<<1, 256, 0, stream>>>(x);

    prep_w_kernel<<<dim3(16, 4), 256, 0, stream>>>(Wq, Wk, Wv, Wo,
                                                   bq, bk, bv, bo, coeffs);

    qkv_gemm_kernel<<<dim3(128, 4, 3), 256, 0, stream>>>(x);

    const int agrid = (BB * HH) * (NN / 128);   // 32 * 16 = 512 blocks
    attn_pass_kernel<0><<<agrid, 256, 0, stream>>>(1, 0); // tA -> tB, caches invl
    attn_pass_kernel<1><<<agrid, 256, 0, stream>>>(2, 1); // tB -> tA, uses invl
    attn_pass_kernel<2><<<agrid, 256, 0, stream>>>(3, 0); // tA -> (acc only)

    out_gemm_kernel<<<dim3(128, 4), 256, 0, stream>>>(d_out);
}

// Round 7
// 226.530 us; speedup vs baseline: 1.5069x; 1.0088x over previous
//
#include <hip/hip_runtime.h>
#include <hip/hip_bf16.h>

typedef __hip_bfloat16 bf16;
typedef __attribute__((ext_vector_type(8))) short short8;   // 8 bf16 = 4 VGPRs
typedef __attribute__((ext_vector_type(4))) short short4v;  // 4 bf16 = 2 VGPRs
typedef __attribute__((ext_vector_type(4))) float f32x4;    // MFMA C/D

#define BB 4
#define NN 2048
#define DD 256
#define HH 8
#define HD 32
#define BN (BB*NN)          // 8192
#define ELEMS (BN*DD)       // 2097152

// ---------------------------------------------------------------------------
// Scratch in module .bss (~33 MB).
// ---------------------------------------------------------------------------
__device__ int g_isf32;
__device__ __attribute__((aligned(256))) unsigned short g_xb [ELEMS]; // x as bf16 [n][k]
__device__ __attribute__((aligned(256))) unsigned short g_qb [ELEMS]; // [bh][n][d] bf16 (pre-scaled)
__device__ __attribute__((aligned(256))) unsigned short g_kb [ELEMS]; // [bh][n][d] bf16
__device__ __attribute__((aligned(256))) unsigned short g_tA [ELEMS]; // [bh][d][n] bf16
__device__ __attribute__((aligned(256))) unsigned short g_tB [ELEMS]; // [bh][d][n] bf16
__device__ __attribute__((aligned(256))) float          g_acc[ELEMS]; // [b][n][D] f32 (c0V+c1T1+c2T2)
__device__ __attribute__((aligned(256))) unsigned short g_mg [ELEMS]; // merged bf16 [n][D] (KIND2 out)
__device__ __attribute__((aligned(256))) unsigned short g_wt [4*DD*DD]; // W^T bf16 [mat][n][k]
__device__ __attribute__((aligned(256))) float g_bias[4*DD];
__device__ __attribute__((aligned(256))) float g_cf[HH*4];
__device__ __attribute__((aligned(256))) float g_invl[BB*HH*NN];      // cached 1/rowsum (pass 1)

__device__ __forceinline__ float b2f(unsigned short u) {
    union { unsigned int i; float f; } c; c.i = ((unsigned int)u) << 16; return c.f;
}
__device__ __forceinline__ unsigned short f2b(float f) {           // safe path
    bf16 h = __float2bfloat16(f);
    return *reinterpret_cast<unsigned short*>(&h);
}
// pack two f32 -> one u32 of two bf16 (RNE).  gfx950 has a 1-instr pk cvt.
#if __has_builtin(__builtin_amdgcn_cvt_pk_bf16_f32)
typedef __attribute__((ext_vector_type(2))) __bf16 bf16x2t;
__device__ __forceinline__ unsigned int pk2(float a, float b) {
    union { bf16x2t v; unsigned int u; } c;
    c.v = __builtin_amdgcn_cvt_pk_bf16_f32(a, b);
    return c.u;
}
#else
__device__ __forceinline__ unsigned int pk2(float a, float b) {
    unsigned int ua = __float_as_uint(a), ub = __float_as_uint(b);
    ua = (ua + 0x7FFFu + ((ua >> 16) & 1u)) >> 16;
    ub = (ub + 0x7FFFu + ((ub >> 16) & 1u)) & 0xFFFF0000u;
    return ua | ub;
}
#endif
__device__ __forceinline__ float ldin(const void* p, int i, int f32m) {
    return f32m ? ((const float*)p)[i] : b2f(((const unsigned short*)p)[i]);
}

// ---------------------------------------------------------------------------
// Kernel 0: dtype probe (unchanged — verified).
// ---------------------------------------------------------------------------
__global__ __launch_bounds__(256) void probe_kernel(const void* __restrict__ x)
{
    __shared__ int cnt;
    if (threadIdx.x == 0) cnt = 0;
    __syncthreads();
    const unsigned short* u = (const unsigned short*)x;
    int w = 0;
    for (int i = threadIdx.x; i < 1024; i += 256) {
        const int e = (u[2 * i] >> 7) & 0xFF;
        if (e < 100 || e > 140) ++w;
    }
    atomicAdd(&cnt, w);
    __syncthreads();
    if (threadIdx.x == 0) g_isf32 = (cnt > 300) ? 1 : 0;
}

// ---------------------------------------------------------------------------
// Kernel 0b (r18): convert x -> bf16 once.  qkv_gemm previously re-loaded
// f32 x and re-converted at EVERY staging step (12 restages per row).
// ---------------------------------------------------------------------------
__global__ __launch_bounds__(256) void prep_x_kernel(const void* __restrict__ x)
{
    const int f32m = g_isf32;
    const size_t i0 = ((size_t)blockIdx.x * 256 + threadIdx.x) * 8;
    if (f32m) {
        const float4 a = *(const float4*)((const float*)x + i0);
        const float4 b = *(const float4*)((const float*)x + i0 + 4);
        union { uint4 v; unsigned int u[4]; } o;
        o.u[0] = pk2(a.x, a.y); o.u[1] = pk2(a.z, a.w);
        o.u[2] = pk2(b.x, b.y); o.u[3] = pk2(b.z, b.w);
        *(uint4*)(g_xb + i0) = o.v;
    } else {
        *(uint4*)(g_xb + i0) = *(const uint4*)((const unsigned short*)x + i0);
    }
}

// ---------------------------------------------------------------------------
// Prep: transpose W[k][n] -> g_wt[mat][n][k] bf16; block(0,0) also preps
// biases + coeffs to f32.
// ---------------------------------------------------------------------------
__global__ __launch_bounds__(256) void prep_w_kernel(
    const void* W0, const void* W1, const void* W2, const void* W3,
    const void* bq, const void* bk, const void* bv, const void* bo,
    const void* coeffs)
{
    const int f32m = g_isf32;
    __shared__ unsigned short tile[64][65];
    const int mat = blockIdx.y;
    const void* W = (mat == 0) ? W0 : (mat == 1) ? W1 : (mat == 2) ? W2 : W3;
    const int k0 = (blockIdx.x >> 2) * 64;
    const int n0 = (blockIdx.x & 3) * 64;
    const int t  = threadIdx.x;

    if (blockIdx.x == 0 && blockIdx.y == 0) {
        g_bias[0 * DD + t] = ldin(bq, t, f32m);
        g_bias[1 * DD + t] = ldin(bk, t, f32m);
        g_bias[2 * DD + t] = ldin(bv, t, f32m);
        g_bias[3 * DD + t] = ldin(bo, t, f32m);
        if (t < 32) g_cf[t] = ldin(coeffs, t, f32m);
    }

    #pragma unroll
    for (int it = 0; it < 16; ++it) {
        const int flat = it * 256 + t;
        const int i = flat >> 6, j = flat & 63;
        tile[j][i] = f2b(ldin(W, (k0 + i) * DD + n0 + j, f32m));
    }
    __syncthreads();
    unsigned short* wt = g_wt + mat * DD * DD;
    #pragma unroll
    for (int it = 0; it < 16; ++it) {
        const int flat = it * 256 + t;
        const int nl = flat >> 6, kl = flat & 63;
        wt[(n0 + nl) * DD + k0 + kl] = tile[nl][kl];
    }
}

// ---------------------------------------------------------------------------
// Kernel 1: QKV projection GEMM — r18: stage x from pre-converted g_xb
// (plain uint4 copy; no per-stage f32 loads / cvt chain).
// ---------------------------------------------------------------------------
__global__ __launch_bounds__(256) void qkv_gemm_kernel()
{
    __shared__ unsigned short xs[64 * 32];
    __shared__ unsigned short wl[64 * 32];
    const int t  = threadIdx.x;
    const int w  = t >> 6, l = t & 63, lg = l >> 4, ln = l & 15;
    const int r0 = blockIdx.x * 64;
    const int n0 = blockIdx.y * 64;
    const int mat = blockIdx.z;
    const unsigned short* wt = g_wt + mat * DD * DD;
    const int sr = t >> 2, sc = (t & 3) * 8;

    f32x4 acc[4] = {{0,0,0,0},{0,0,0,0},{0,0,0,0},{0,0,0,0}};

    for (int kc = 0; kc < DD; kc += 32) {
        __syncthreads();
        *(uint4*)(xs + sr * 32 + sc) =
            *(const uint4*)(g_xb + (size_t)(r0 + sr) * DD + kc + sc);
        *(uint4*)(wl + sr * 32 + sc) =
            *(const uint4*)(wt + (size_t)(n0 + sr) * DD + kc + sc);
        __syncthreads();
        const short8 af = *(const short8*)(xs + (w * 16 + ln) * 32 + lg * 8);
        #pragma unroll
        for (int s = 0; s < 4; ++s) {
            const short8 bfr = *(const short8*)(wl + (s * 16 + ln) * 32 + lg * 8);
            acc[s] = __builtin_amdgcn_mfma_f32_16x16x32_bf16(af, bfr, acc[s], 0, 0, 0);
        }
    }

    const float QS = 0.17677669529663687f * 1.4426950408889634f; // scale*log2e
    #pragma unroll
    for (int s = 0; s < 4; ++s) {
        const int j = n0 + s * 16 + ln;
        const float bias = g_bias[mat * DD + j];
        const int h = j >> 5, dd = j & 31;
        #pragma unroll
        for (int r = 0; r < 4; ++r) {
            const int rn = r0 + w * 16 + lg * 4 + r;
            const int b = rn >> 11, n = rn & (NN - 1);
            const int bh = b * HH + h;
            const float val = acc[s][r] + bias;
            if (mat == 0) {
                g_qb[((size_t)bh * NN + n) * HD + dd] = f2b(val * QS);
            } else if (mat == 1) {
                g_kb[((size_t)bh * NN + n) * HD + dd] = f2b(val);
            } else {
                g_tA[((size_t)bh * HD + dd) * NN + n] = f2b(val);
                g_acc[(size_t)rn * DD + j] = g_cf[h * 4] * val;
            }
        }
    }
}

// ---------------------------------------------------------------------------
// Kernel 2: attention pass, q-tile 128 (r17 structure, verified 48.5us).
//  KIND=0: scalar lsum, caches 1/rowsum to g_invl; tout + g_acc RMW.
//  KIND=1: skips row-sum work, loads cached invl; tout + g_acc RMW.
//  KIND=2 (r18): final pass — no tout; reads g_acc, writes MERGED result as
//    bf16 to g_mg (numerically identical to the old staged f2b in out_gemm;
//    halves this pass's write traffic and removes out_gemm's f32 restages).
// ---------------------------------------------------------------------------
template<int KIND>
__global__ __launch_bounds__(256) void attn_pass_kernel(const int kidx, const int dir)
{
    __shared__ float osh[2][128][33];   // wave-pair partials (+1 pad) 33.8 KB
    __shared__ float lsh[4][128];

    const unsigned short* __restrict__ tin  = dir ? g_tB : g_tA;
    unsigned short*       __restrict__ tout = dir ? g_tA : g_tB;

    const int tid = threadIdx.x;
    const int w   = tid >> 6;
    const int l   = tid & 63;
    const int lg  = l >> 4;
    const int ln  = l & 15;

    // XCD swizzle: bi%8 selects XCD; each XCD gets 4 bh, all 16 q-tiles of
    // a bh stay on one XCD.
    const int bi = blockIdx.x;                 // grid 512
    const int bh = (bi & 7) * 4 + ((bi >> 3) & 3);   // b*H + h
    const int qt = bi >> 5;                    // 0..15
    const int h  = bh & (HH - 1);
    const int b  = bh >> 3;
    const int q0 = qt * 128;

    short8 qf[8];
    #pragma unroll
    for (int qi = 0; qi < 8; ++qi)
        qf[qi] = *(const short8*)(g_qb +
            ((size_t)bh * NN + q0 + qi * 16 + ln) * HD + lg * 8);

    const unsigned short* kb = g_kb + (size_t)bh * NN * HD;
    const unsigned short* tb = tin  + (size_t)bh * HD * NN;

    f32x4 oacc[8][2];
    #pragma unroll
    for (int qi = 0; qi < 8; ++qi) { oacc[qi][0] = (f32x4){0,0,0,0}; oacc[qi][1] = (f32x4){0,0,0,0}; }
    float lsum[8] = {0.f, 0.f, 0.f, 0.f, 0.f, 0.f, 0.f, 0.f};
    const f32x4 zero = {0.f, 0.f, 0.f, 0.f};

    for (int it = 0; it < 16; ++it) {
        const int k0 = it * 128 + w * 32;   // this wave's 32-key strip
        const short8 kf0 = *(const short8*)(kb + (size_t)(k0 + ln) * HD + lg * 8);
        const short8 kf1 = *(const short8*)(kb + (size_t)(k0 + 16 + ln) * HD + lg * 8);

#if __has_builtin(__builtin_amdgcn_mfma_f32_16x16x16bf16_1k)
        // T^T A-frags for K=16 PV: [c=key-chunk][hf=dim-half], 8B each
        short4v tf[2][2];
        #pragma unroll
        for (int c = 0; c < 2; ++c)
            #pragma unroll
            for (int hf = 0; hf < 2; ++hf)
                tf[c][hf] = *(const short4v*)(tb +
                    (size_t)(hf * 16 + ln) * NN + k0 + c * 16 + lg * 4);

        #pragma unroll
        for (int qi = 0; qi < 8; ++qi) {
            f32x4 s0 = __builtin_amdgcn_mfma_f32_16x16x32_bf16(kf0, qf[qi], zero, 0, 0, 0);
            f32x4 s1 = __builtin_amdgcn_mfma_f32_16x16x32_bf16(kf1, qf[qi], zero, 0, 0, 0);
            float p[8];
            #pragma unroll
            for (int r = 0; r < 4; ++r) {
                p[r]     = __builtin_amdgcn_exp2f(s0[r]);
                p[4 + r] = __builtin_amdgcn_exp2f(s1[r]);
                if (KIND == 0) lsum[qi] += p[r] + p[4 + r];
            }
            union { unsigned int u[2]; short4v s; } pb0, pb1;
            pb0.u[0] = pk2(p[0], p[1]); pb0.u[1] = pk2(p[2], p[3]);
            pb1.u[0] = pk2(p[4], p[5]); pb1.u[1] = pk2(p[6], p[7]);
            oacc[qi][0] = __builtin_amdgcn_mfma_f32_16x16x16bf16_1k(tf[0][0], pb0.s, oacc[qi][0], 0, 0, 0);
            oacc[qi][1] = __builtin_amdgcn_mfma_f32_16x16x16bf16_1k(tf[0][1], pb0.s, oacc[qi][1], 0, 0, 0);
            oacc[qi][0] = __builtin_amdgcn_mfma_f32_16x16x16bf16_1k(tf[1][0], pb1.s, oacc[qi][0], 0, 0, 0);
            oacc[qi][1] = __builtin_amdgcn_mfma_f32_16x16x16bf16_1k(tf[1][1], pb1.s, oacc[qi][1], 0, 0, 0);
        }
#else
        // fallback: r10's verified shuffle-transpose path (K=32 PV)
        const short8 tf0 = *(const short8*)(tb + (size_t)ln * NN + k0 + lg * 8);
        const short8 tf1 = *(const short8*)(tb + (size_t)(ln + 16) * NN + k0 + lg * 8);
        #pragma unroll
        for (int qi = 0; qi < 8; ++qi) {
            f32x4 s0 = __builtin_amdgcn_mfma_f32_16x16x32_bf16(kf0, qf[qi], zero, 0, 0, 0);
            f32x4 s1 = __builtin_amdgcn_mfma_f32_16x16x32_bf16(kf1, qf[qi], zero, 0, 0, 0);
            float p[8];
            #pragma unroll
            for (int r = 0; r < 4; ++r) {
                p[r]     = __builtin_amdgcn_exp2f(s0[r]);
                p[4 + r] = __builtin_amdgcn_exp2f(s1[r]);
                if (KIND == 0) lsum[qi] += p[r] + p[4 + r];
            }
            const unsigned int pk0 = pk2(p[0], p[1]);
            const unsigned int pk1 = pk2(p[2], p[3]);
            const unsigned int pk2v = pk2(p[4], p[5]);
            const unsigned int pk3 = pk2(p[6], p[7]);
            int bi2[4];
            #pragma unroll
            for (int j = 0; j < 4; ++j) {
                const int srcLane = (((2 * lg + (j >> 1)) & 3) << 4) + ln;
                const int lo = __shfl((j & 1) ? (int)pk1 : (int)pk0, srcLane, 64);
                const int hi = __shfl((j & 1) ? (int)pk3 : (int)pk2v, srcLane, 64);
                bi2[j] = (lg < 2) ? lo : hi;
            }
            union { int i[4]; short8 s; } pf;
            pf.i[0] = bi2[0]; pf.i[1] = bi2[1]; pf.i[2] = bi2[2]; pf.i[3] = bi2[3];
            oacc[qi][0] = __builtin_amdgcn_mfma_f32_16x16x32_bf16(tf0, pf.s, oacc[qi][0], 0, 0, 0);
            oacc[qi][1] = __builtin_amdgcn_mfma_f32_16x16x32_bf16(tf1, pf.s, oacc[qi][1], 0, 0, 0);
        }
#endif
    }

    // lsum: reduce across lg groups (lanes sharing ln) — pass 1 only
    if (KIND == 0) {
        #pragma unroll
        for (int qi = 0; qi < 8; ++qi) {
            lsum[qi] += __shfl_xor(lsum[qi], 16, 64);
            lsum[qi] += __shfl_xor(lsum[qi], 32, 64);
        }
        if (lg == 0) {
            #pragma unroll
            for (int qi = 0; qi < 8; ++qi) lsh[w][qi * 16 + ln] = lsum[qi];
        }
    }

    // wave-pair combine: waves 0/1 write, waves 2/3 accumulate.
    // row q = qi*16+ln, col d = hf*16+lg*4+r
    if (w < 2) {
        #pragma unroll
        for (int qi = 0; qi < 8; ++qi)
            #pragma unroll
            for (int hf = 0; hf < 2; ++hf)
                #pragma unroll
                for (int r = 0; r < 4; ++r)
                    osh[w][qi * 16 + ln][hf * 16 + lg * 4 + r] = oacc[qi][hf][r];
    }
    __syncthreads();
    if (w >= 2) {
        #pragma unroll
        for (int qi = 0; qi < 8; ++qi)
            #pragma unroll
            for (int hf = 0; hf < 2; ++hf)
                #pragma unroll
                for (int r = 0; r < 4; ++r)
                    osh[w - 2][qi * 16 + ln][hf * 16 + lg * 4 + r] += oacc[qi][hf][r];
    }
    __syncthreads();

    // combine 2 partials; thread t: q = t&127, dims (t>>7)*16 ..+15
    {
        const int q  = tid & 127;
        const int db = (tid >> 7) * 16;
        float invl;
        if (KIND == 0) {
            invl = 1.0f / (lsh[0][q] + lsh[1][q] + lsh[2][q] + lsh[3][q]);
            if (db == 0) g_invl[(size_t)bh * NN + q0 + q] = invl;
        } else {
            invl = g_invl[(size_t)bh * NN + q0 + q];
        }
        const float ck = g_cf[h * 4 + kidx];
        #pragma unroll
        for (int dd = 0; dd < 16; ++dd) {
            const int d = db + dd;
            const float val = (osh[0][q][d] + osh[1][q][d]) * invl;
            const size_t gi = ((size_t)(b * NN + q0 + q)) * DD + h * HD + d;
            if (KIND != 2) {
                tout[((size_t)bh * HD + d) * NN + q0 + q] = f2b(val);
                g_acc[gi] += ck * val;
            } else {
                g_mg[gi] = f2b(g_acc[gi] + ck * val);   // final merged, bf16
            }
        }
    }
}

// ---------------------------------------------------------------------------
// Kernel 3: output projection GEMM — r18: stage from pre-merged bf16 g_mg
// (plain uint4 copy; no f32 restages / cvt chain).
// ---------------------------------------------------------------------------
__global__ __launch_bounds__(256) void out_gemm_kernel(void* __restrict__ out)
{
    __shared__ unsigned short xs[64 * 32];
    __shared__ unsigned short wl[64 * 32];
    const int f32m = g_isf32;
    const int t  = threadIdx.x;
    const int w  = t >> 6, l = t & 63, lg = l >> 4, ln = l & 15;
    const int r0 = blockIdx.x * 64;
    const int n0 = blockIdx.y * 64;
    const unsigned short* wt = g_wt + 3 * DD * DD;
    const int sr = t >> 2, sc = (t & 3) * 8;

    f32x4 acc[4] = {{0,0,0,0},{0,0,0,0},{0,0,0,0},{0,0,0,0}};

    for (int kc = 0; kc < DD; kc += 32) {
        __syncthreads();
        *(uint4*)(xs + sr * 32 + sc) =
            *(const uint4*)(g_mg + (size_t)(r0 + sr) * DD + kc + sc);
        *(uint4*)(wl + sr * 32 + sc) =
            *(const uint4*)(wt + (size_t)(n0 + sr) * DD + kc + sc);
        __syncthreads();
        const short8 af = *(const short8*)(xs + (w * 16 + ln) * 32 + lg * 8);
        #pragma unroll
        for (int s = 0; s < 4; ++s) {
            const short8 bfr = *(const short8*)(wl + (s * 16 + ln) * 32 + lg * 8);
            acc[s] = __builtin_amdgcn_mfma_f32_16x16x32_bf16(af, bfr, acc[s], 0, 0, 0);
        }
    }

    #pragma unroll
    for (int s = 0; s < 4; ++s) {
        const int j = n0 + s * 16 + ln;
        const float bias = g_bias[3 * DD + j];
        #pragma unroll
        for (int r = 0; r < 4; ++r) {
            const int rn = r0 + w * 16 + lg * 4 + r;
            const float val = acc[s][r] + bias;
            if (f32m) ((float*)out)[(size_t)rn * DD + j] = val;
            else      ((bf16*)out)[(size_t)rn * DD + j] = __float2bfloat16(val);
        }
    }
}

// ---------------------------------------------------------------------------
extern "C" void kernel_launch(void* const* d_in, const int* in_sizes, int n_in,
                              void* d_out, int out_size, void* d_ws, size_t ws_size,
                              hipStream_t stream)
{
    const void* x      = d_in[0];
    const void* Wq     = d_in[1];
    const void* bq     = d_in[2];
    const void* Wk     = d_in[3];
    const void* bk     = d_in[4];
    const void* Wv     = d_in[5];
    const void* bv     = d_in[6];
    const void* Wo     = d_in[7];
    const void* bo     = d_in[8];
    const void* coeffs = d_in[9];
    (void)d_ws; (void)ws_size; (void)in_sizes; (void)n_in; (void)out_size;

    probe_kernel<<<1, 256, 0, stream>>>(x);

    prep_x_kernel<<<ELEMS / (256 * 8), 256, 0, stream>>>(x);
    prep_w_kernel<<<dim3(16, 4), 256, 0, stream>>>(Wq, Wk, Wv, Wo,
                                                   bq, bk, bv, bo, coeffs);

    qkv_gemm_kernel<<<dim3(128, 4, 3), 256, 0, stream>>>();

    const int agrid = (BB * HH) * (NN / 128);   // 32 * 16 = 512 blocks
    attn_pass_kernel<0><<<agrid, 256, 0, stream>>>(1, 0); // tA -> tB, caches invl
    attn_pass_kernel<1><<<agrid, 256, 0, stream>>>(2, 1); // tB -> tA, uses invl
    attn_pass_kernel<2><<<agrid, 256, 0, stream>>>(3, 0); // tA -> g_mg (merged)

    out_gemm_kernel<<<dim3(128, 4), 256, 0, stream>>>(d_out);
}